// Round 23
// baseline (40.654 us; speedup 1.0000x reference)
//
#include <hip/hip_runtime.h>
#include <hip/hip_bf16.h>

// GlobalPoolDistance: RBF-kernel MMD over 3x3 patch unfolds (8,3,64,64) f32.
// N = 62*62 = 3844 patches, d = 27 (padded K=32). SIG2 = 0.2916.
// R23 = R22 scaled to 512x512 tiles (isolated change; traffic model now
// predictive: R22's halving 1 -> 0.5 B/pair bought 3us as modeled). Per
// 4-wave block: A = 8 frags/wave (128 rows, plain loads + keep-alive tie),
// B panel 32KB LDS (32 x 1KB chunks, staged by all 4 waves), 32 cg-steps of
// the 8-chain skip-guarded BODY. 0.24 B/pair -> 60 MB total -> ~6us traffic.
// 1088 blocks = 8 x 136 (exact bijective XCD swizzle). Sync identical to
// R22: NO manual vmcnt (R11/R13 lesson); __syncthreads' vmcnt(0) drain
// covers A plain loads and the B staging DMA. Live ~80 VGPR < (256,4)'s
// 128 cap -> no spills.
// Math recap (R17/R18): single-MFMA gram, diag exact by construction
// (p = -s'/2 over ROUNDED bf16 values, baked hi/lo across pad-col pairs);
// negligible-fragment skip (epilogue only when __any(g > -40); skipped
// contribution < 2e-12 vs 1e-5 threshold); weights folded into the store
// (xy=-2, sym diag=+1, off-diag=+2) -> answer = sum(part)/(8N^2).
//
// ws: Am|Bm [16][4096][32] bf16 (2 x 4,194,304 B) + part[1088] f32.

#define NP    3844
#define NPAD  4096
#define KP    32

#define XYB   512      // 8 * 8 * 8 xy tile-blocks
#define NBLK  1088     // + 2 * 8 * 36 tri tile-blocks = 8 * 136

static constexpr float L_F   = 4.9475824173972215f;   // log2(e)/0.2916
static constexpr float C2L_F = 9.895164834794443f;    // 2*L

using bf16x8 = __attribute__((ext_vector_type(8))) short;
using f32x4  = __attribute__((ext_vector_type(4))) float;

#define MFMA16(a, b, c) __builtin_amdgcn_mfma_f32_16x16x32_bf16((a), (b), (c), 0, 0, 0)

__device__ inline unsigned short f2bf(float f) {
    union { float f; unsigned u; } v; v.f = f;
    unsigned r = v.u + 0x7FFFu + ((v.u >> 16) & 1u);   // RNE (no NaN inputs)
    return (unsigned short)(r >> 16);
}
__device__ inline float bf2f(unsigned short h) {
    union { unsigned u; float f; } v; v.u = ((unsigned)h) << 16;
    return v.f;
}
__device__ inline void pack_store(unsigned short* dst, const unsigned short* v) {
    uint4* d = (uint4*)dst;
#pragma unroll
    for (int q = 0; q < 4; ++q) {
        unsigned w0 = (unsigned)v[8 * q + 0] | ((unsigned)v[8 * q + 1] << 16);
        unsigned w1 = (unsigned)v[8 * q + 2] | ((unsigned)v[8 * q + 3] << 16);
        unsigned w2 = (unsigned)v[8 * q + 4] | ((unsigned)v[8 * q + 5] << 16);
        unsigned w3 = (unsigned)v[8 * q + 6] | ((unsigned)v[8 * q + 7] << 16);
        d[q] = make_uint4(w0, w1, w2, w3);
    }
}

// One thread per (im, patch). A data = bf16(2L*v); B data = bf16(v);
// s' = sum over ROUNDED values; p = -s'/2 split hi/lo across column pairs.
__global__ __launch_bounds__(256) void gp_prep(const float* __restrict__ x,
                                               const float* __restrict__ y,
                                               unsigned short* __restrict__ Am,
                                               unsigned short* __restrict__ Bm) {
    int i = blockIdx.x * 256 + threadIdx.x;          // 16*NPAD = 65536
    if (i >= 16 * NPAD) return;
    int n = i % NPAD, im = i / NPAD;
    int b = im & 7;
    const float* src = (im >> 3) ? y : x;

    const unsigned short ONE = f2bf(1.0f);           // exact
    unsigned short hA[32], hB[32];
#pragma unroll
    for (int k = 0; k < 32; ++k) { hA[k] = 0; hB[k] = 0; }

    if (n < NP) {
        int r = n / 62, c = n % 62;
        float s = 0.0f;
#pragma unroll
        for (int ch = 0; ch < 3; ++ch)
#pragma unroll
            for (int pr = 0; pr < 3; ++pr)
#pragma unroll
                for (int pc = 0; pc < 3; ++pc) {
                    int k = ch * 9 + pr * 3 + pc;
                    float v = src[(((b * 3 + ch) * 64) + r + pr) * 64 + (c + pc)];
                    unsigned short ah = f2bf(C2L_F * v);
                    unsigned short bh = f2bf(v);
                    hA[k] = ah; hB[k] = bh;
                    s = fmaf(bf2f(ah), bf2f(bh), s);   // s' over ROUNDED values
                }
        float p = -0.5f * s;
        // A-side p: cols 27(hi)/28(lo), matched by B27=B28=1
        hA[27] = f2bf(p); hA[28] = f2bf(p - bf2f(hA[27]));
        hA[29] = ONE; hA[30] = ONE;
        // B-side p: cols 29(hi)/30(lo), matched by A29=A30=1
        hB[27] = ONE; hB[28] = ONE;
        hB[29] = f2bf(p); hB[30] = f2bf(p - bf2f(hB[29]));
    } else {
        // phantom: row/col contributes exp2(-1e30) = 0 against real AND phantom
        hA[27] = f2bf(-1e30f); hA[29] = ONE; hA[30] = ONE;
        hB[27] = ONE; hB[28] = ONE; hB[29] = f2bf(-1e30f);
    }

    pack_store(Am + (size_t)i * KP, hA);
    pack_store(Bm + (size_t)i * KP, hB);
}

// global -> LDS direct (1KB per call: 64 lanes x 16B), compiler-visible.
__device__ inline void glds(const unsigned short* p, char* lptr) {
    __builtin_amdgcn_global_load_lds(
        (const __attribute__((address_space(1))) void*)p,
        (__attribute__((address_space(3))) void*)lptr, 16, 0, 0);
}

// 8 single-MFMA chains (128 rows x 16 cols); epilogue (32 exp2 + adds)
// SKIPPED when every g < -40 (wave-uniform test): exp2(g) < 2^-40 each,
// total skipped contribution to the output < 2e-12.
#define BODY8(BHC)                                                           \
    do {                                                                     \
        const f32x4 Z = {0.f, 0.f, 0.f, 0.f};                                \
        f32x4 g0 = MFMA16(ah0, BHC, Z); f32x4 g1 = MFMA16(ah1, BHC, Z);      \
        f32x4 g2 = MFMA16(ah2, BHC, Z); f32x4 g3 = MFMA16(ah3, BHC, Z);      \
        f32x4 g4 = MFMA16(ah4, BHC, Z); f32x4 g5 = MFMA16(ah5, BHC, Z);      \
        f32x4 g6 = MFMA16(ah6, BHC, Z); f32x4 g7 = MFMA16(ah7, BHC, Z);      \
        float m0 = fmaxf(fmaxf(fmaxf(g0[0], g0[1]), g0[2]), g0[3]);          \
        float m1 = fmaxf(fmaxf(fmaxf(g1[0], g1[1]), g1[2]), g1[3]);          \
        float m2 = fmaxf(fmaxf(fmaxf(g2[0], g2[1]), g2[2]), g2[3]);          \
        float m3 = fmaxf(fmaxf(fmaxf(g3[0], g3[1]), g3[2]), g3[3]);          \
        float m4 = fmaxf(fmaxf(fmaxf(g4[0], g4[1]), g4[2]), g4[3]);          \
        float m5 = fmaxf(fmaxf(fmaxf(g5[0], g5[1]), g5[2]), g5[3]);          \
        float m6 = fmaxf(fmaxf(fmaxf(g6[0], g6[1]), g6[2]), g6[3]);          \
        float m7 = fmaxf(fmaxf(fmaxf(g7[0], g7[1]), g7[2]), g7[3]);          \
        float mm = fmaxf(fmaxf(fmaxf(fmaxf(fmaxf(fmaxf(fmaxf(m0, m1), m2),   \
                         m3), m4), m5), m6), m7);                            \
        if (__any(mm > -40.0f)) {                                            \
            s0 += __builtin_amdgcn_exp2f(g0[0]); s1 += __builtin_amdgcn_exp2f(g0[1]); \
            s2 += __builtin_amdgcn_exp2f(g0[2]); s3 += __builtin_amdgcn_exp2f(g0[3]); \
            s0 += __builtin_amdgcn_exp2f(g1[0]); s1 += __builtin_amdgcn_exp2f(g1[1]); \
            s2 += __builtin_amdgcn_exp2f(g1[2]); s3 += __builtin_amdgcn_exp2f(g1[3]); \
            s0 += __builtin_amdgcn_exp2f(g2[0]); s1 += __builtin_amdgcn_exp2f(g2[1]); \
            s2 += __builtin_amdgcn_exp2f(g2[2]); s3 += __builtin_amdgcn_exp2f(g2[3]); \
            s0 += __builtin_amdgcn_exp2f(g3[0]); s1 += __builtin_amdgcn_exp2f(g3[1]); \
            s2 += __builtin_amdgcn_exp2f(g3[2]); s3 += __builtin_amdgcn_exp2f(g3[3]); \
            s0 += __builtin_amdgcn_exp2f(g4[0]); s1 += __builtin_amdgcn_exp2f(g4[1]); \
            s2 += __builtin_amdgcn_exp2f(g4[2]); s3 += __builtin_amdgcn_exp2f(g4[3]); \
            s0 += __builtin_amdgcn_exp2f(g5[0]); s1 += __builtin_amdgcn_exp2f(g5[1]); \
            s2 += __builtin_amdgcn_exp2f(g5[2]); s3 += __builtin_amdgcn_exp2f(g5[3]); \
            s0 += __builtin_amdgcn_exp2f(g6[0]); s1 += __builtin_amdgcn_exp2f(g6[1]); \
            s2 += __builtin_amdgcn_exp2f(g6[2]); s3 += __builtin_amdgcn_exp2f(g6[3]); \
            s0 += __builtin_amdgcn_exp2f(g7[0]); s1 += __builtin_amdgcn_exp2f(g7[1]); \
            s2 += __builtin_amdgcn_exp2f(g7[2]); s3 += __builtin_amdgcn_exp2f(g7[3]); \
        }                                                                    \
    } while (0)

// 512x512 tile per 4-wave block. B panel (32KB) in LDS shared by 4 waves;
// wave wv owns rows [si*512 + wv*128, +128) (8 A-frags in registers).
// No manual waitcnt: __syncthreads' vmcnt(0) drain covers A plain loads
// (kept live by the empty-asm tie) and the B staging DMA.
__global__ __launch_bounds__(256, 4) void gp_pairs23(const unsigned short* __restrict__ Am,
                                                     const unsigned short* __restrict__ Bm,
                                                     float* __restrict__ part) {
    __shared__ __align__(16) char ldsB[32768];
    __shared__ float red[4];

    const int phys = blockIdx.x;
    const int blk = (phys & 7) * 136 + (phys >> 3);   // bijective, 1088 = 8*136

    const int t = threadIdx.x;
    const int wv = t >> 6, l = t & 63;
    const int l15 = l & 15, lhi = l >> 4;

    int type, b, si, sj;
    float wt;
    if (blk < XYB) {
        type = 0; b = blk >> 6;
        int rr = blk & 63; si = rr >> 3; sj = rr & 7;
        wt = -2.0f;
    } else {
        int id2 = blk - XYB;
        type = 1 + id2 / 288;
        int r = id2 % 288; b = r / 36; int t2 = r % 36;
        sj = (int)((sqrtf(8.0f * (float)t2 + 1.0f) - 1.0f) * 0.5f);
        while ((sj + 1) * (sj + 2) / 2 <= t2) ++sj;
        while (sj * (sj + 1) / 2 > t2) --sj;
        si = t2 - sj * (sj + 1) / 2;                  // si <= sj
        wt = (si == sj) ? 1.0f : 2.0f;
    }
    int imA, imB;
    if (type == 0)      { imA = b;     imB = 8 + b; }
    else if (type == 1) { imA = b;     imB = b;     }
    else                { imA = 8 + b; imB = 8 + b; }

    // A fragments: 128 rows for this wave (8 frags, 32 VGPR), plain loads +
    // keep-alive tie (cannot be sunk/remat'd; syncthreads drains the loads).
    const size_t eA = ((size_t)(imA * NPAD + si * 512 + wv * 128 + l15)) * KP + lhi * 8;
    const unsigned short* pA = Am + eA;
    bf16x8 ah0 = *(const bf16x8*)(pA);
    bf16x8 ah1 = *(const bf16x8*)(pA + 512);
    bf16x8 ah2 = *(const bf16x8*)(pA + 1024);
    bf16x8 ah3 = *(const bf16x8*)(pA + 1536);
    bf16x8 ah4 = *(const bf16x8*)(pA + 2048);
    bf16x8 ah5 = *(const bf16x8*)(pA + 2560);
    bf16x8 ah6 = *(const bf16x8*)(pA + 3072);
    bf16x8 ah7 = *(const bf16x8*)(pA + 3584);
    asm volatile("" : "+v"(ah0), "+v"(ah1), "+v"(ah2), "+v"(ah3),
                      "+v"(ah4), "+v"(ah5), "+v"(ah6), "+v"(ah7));

    // Stage the 512-col B panel (32KB) cooperatively: 32 chunks of 1KB;
    // wave wv stages chunks wv*8..wv*8+7 (wave-uniform LDS dst, per-lane src).
#pragma unroll
    for (int j = 0; j < 8; ++j) {
        const int q = wv * 8 + j;
        const unsigned short* src = Bm
            + ((size_t)(imB * NPAD + sj * 512 + q * 16 + l15)) * KP + lhi * 8;
        glds(src, ldsB + q * 1024);
    }
    __syncthreads();   // vmcnt(0)+lgkmcnt(0) drain (A loads + staging) + barrier

    float s0 = 0.f, s1 = 0.f, s2 = 0.f, s3 = 0.f;

    // 32 barrier-free cg steps: B frag from LDS (conflict-free lane*16B),
    // 8 MFMA + skip-guarded 32 exp2 each.
#pragma unroll
    for (int cg = 0; cg < 32; ++cg) {
        const bf16x8 bhc = *(const bf16x8*)(ldsB + cg * 1024 + l * 16);
        BODY8(bhc);
    }

    float sacc = (s0 + s1) + (s2 + s3);

    // wave reduce; cross-wave combine; one plain store per block (no atomics)
#pragma unroll
    for (int o = 32; o > 0; o >>= 1) sacc += __shfl_down(sacc, o, 64);
    if (l == 0) red[wv] = sacc;
    __syncthreads();
    if (t == 0) part[blk] = wt * ((red[0] + red[1]) + (red[2] + red[3]));
}

// ONE block x 1024 threads (16 waves): coalesced sum of the 1088 weighted
// block partials; answer = sum / (8 N^2).
__global__ __launch_bounds__(1024) void gp_finish(const float* __restrict__ part,
                                                  float* __restrict__ out) {
    __shared__ float red[16];
    const int t = threadIdx.x;
    const int wv = t >> 6, l = t & 63;

    float s = 0.0f;
    for (int i = t; i < NBLK; i += 1024) s += part[i];
#pragma unroll
    for (int o = 32; o > 0; o >>= 1) s += __shfl_down(s, o, 64);
    if (l == 0) red[wv] = s;
    __syncthreads();
    if (t == 0) {
        double d = 0.0;
#pragma unroll
        for (int i = 0; i < 16; ++i) d += (double)red[i];
        out[0] = (float)(d / (8.0 * (double)NP * (double)NP));
    }
}

extern "C" void kernel_launch(void* const* d_in, const int* in_sizes, int n_in,
                              void* d_out, int out_size, void* d_ws, size_t ws_size,
                              hipStream_t stream) {
    const float* x = (const float*)d_in[0];
    const float* y = (const float*)d_in[1];
    const size_t MSZ = (size_t)16 * NPAD * KP;
    unsigned short* Am = (unsigned short*)d_ws;
    unsigned short* Bm = Am + MSZ;
    float* part = (float*)(Bm + MSZ);

    gp_prep<<<(16 * NPAD) / 256, 256, 0, stream>>>(x, y, Am, Bm);
    gp_pairs23<<<NBLK, 256, 0, stream>>>(Am, Bm, part);
    gp_finish<<<1, 1024, 0, stream>>>(part, (float*)d_out);
}

// Round 24
// 38.253 us; speedup vs baseline: 1.0628x; 1.0628x over previous
//
#include <hip/hip_runtime.h>
#include <hip/hip_bf16.h>

// GlobalPoolDistance: RBF-kernel MMD over 3x3 patch unfolds (8,3,64,64) f32.
// N = 62*62 = 3844 patches, d = 27 (padded K=32). SIG2 = 0.2916.
// R24 = R22 (best, 37.1us) with the B-panel staging split into TWO 8KB
// halves, double-buffered with __syncthreads only: stage half0 -> barrier
// (drains A loads + half0 DMA) -> issue half1 staging -> compute cg0..7
// from half0 (half1 DMA in flight underneath) -> barrier (vmcnt(0) drains
// half1) -> compute cg8..15. Hides ~half the per-block staging latency.
// R23 lesson: 512^2 tiles regressed (4.25 block-generations tail + 2x
// longer serial prologue); tile size stays 256^2 / 4224 blocks (16.5/CU).
// Sync discipline unchanged from R22: NO manual vmcnt (R11/R13 lesson);
// A = plain loads + empty-asm keep-alive tie (R14-proven); staging =
// compiler-visible global_load_lds; barriers do all draining.
// Math recap (R17/R18): single-MFMA gram, diag exact by construction
// (p = -s'/2 over ROUNDED bf16 values, baked hi/lo across pad-col pairs);
// negligible-fragment skip (epilogue only when __any(g > -40); skipped
// contribution < 2e-12 vs 1e-5 threshold); weights folded into the store
// (xy=-2, sym diag=+1, off-diag=+2) -> answer = sum(part)/(8N^2).
//
// ws: Am|Bm [16][4096][32] bf16 (2 x 4,194,304 B) + part[4224] f32.

#define NP    3844
#define NPAD  4096
#define KP    32

#define XYB   2048     // 8 * 16 * 16 xy tile-blocks
#define NBLK  4224     // + 2 * 8 * 136 tri tile-blocks = 8 * 528

static constexpr float L_F   = 4.9475824173972215f;   // log2(e)/0.2916
static constexpr float C2L_F = 9.895164834794443f;    // 2*L

using bf16x8 = __attribute__((ext_vector_type(8))) short;
using f32x4  = __attribute__((ext_vector_type(4))) float;

#define MFMA16(a, b, c) __builtin_amdgcn_mfma_f32_16x16x32_bf16((a), (b), (c), 0, 0, 0)

__device__ inline unsigned short f2bf(float f) {
    union { float f; unsigned u; } v; v.f = f;
    unsigned r = v.u + 0x7FFFu + ((v.u >> 16) & 1u);   // RNE (no NaN inputs)
    return (unsigned short)(r >> 16);
}
__device__ inline float bf2f(unsigned short h) {
    union { unsigned u; float f; } v; v.u = ((unsigned)h) << 16;
    return v.f;
}
__device__ inline void pack_store(unsigned short* dst, const unsigned short* v) {
    uint4* d = (uint4*)dst;
#pragma unroll
    for (int q = 0; q < 4; ++q) {
        unsigned w0 = (unsigned)v[8 * q + 0] | ((unsigned)v[8 * q + 1] << 16);
        unsigned w1 = (unsigned)v[8 * q + 2] | ((unsigned)v[8 * q + 3] << 16);
        unsigned w2 = (unsigned)v[8 * q + 4] | ((unsigned)v[8 * q + 5] << 16);
        unsigned w3 = (unsigned)v[8 * q + 6] | ((unsigned)v[8 * q + 7] << 16);
        d[q] = make_uint4(w0, w1, w2, w3);
    }
}

// One thread per (im, patch). A data = bf16(2L*v); B data = bf16(v);
// s' = sum over ROUNDED values; p = -s'/2 split hi/lo across column pairs.
__global__ __launch_bounds__(256) void gp_prep(const float* __restrict__ x,
                                               const float* __restrict__ y,
                                               unsigned short* __restrict__ Am,
                                               unsigned short* __restrict__ Bm) {
    int i = blockIdx.x * 256 + threadIdx.x;          // 16*NPAD = 65536
    if (i >= 16 * NPAD) return;
    int n = i % NPAD, im = i / NPAD;
    int b = im & 7;
    const float* src = (im >> 3) ? y : x;

    const unsigned short ONE = f2bf(1.0f);           // exact
    unsigned short hA[32], hB[32];
#pragma unroll
    for (int k = 0; k < 32; ++k) { hA[k] = 0; hB[k] = 0; }

    if (n < NP) {
        int r = n / 62, c = n % 62;
        float s = 0.0f;
#pragma unroll
        for (int ch = 0; ch < 3; ++ch)
#pragma unroll
            for (int pr = 0; pr < 3; ++pr)
#pragma unroll
                for (int pc = 0; pc < 3; ++pc) {
                    int k = ch * 9 + pr * 3 + pc;
                    float v = src[(((b * 3 + ch) * 64) + r + pr) * 64 + (c + pc)];
                    unsigned short ah = f2bf(C2L_F * v);
                    unsigned short bh = f2bf(v);
                    hA[k] = ah; hB[k] = bh;
                    s = fmaf(bf2f(ah), bf2f(bh), s);   // s' over ROUNDED values
                }
        float p = -0.5f * s;
        // A-side p: cols 27(hi)/28(lo), matched by B27=B28=1
        hA[27] = f2bf(p); hA[28] = f2bf(p - bf2f(hA[27]));
        hA[29] = ONE; hA[30] = ONE;
        // B-side p: cols 29(hi)/30(lo), matched by A29=A30=1
        hB[27] = ONE; hB[28] = ONE;
        hB[29] = f2bf(p); hB[30] = f2bf(p - bf2f(hB[29]));
    } else {
        // phantom: row/col contributes exp2(-1e30) = 0 against real AND phantom
        hA[27] = f2bf(-1e30f); hA[29] = ONE; hA[30] = ONE;
        hB[27] = ONE; hB[28] = ONE; hB[29] = f2bf(-1e30f);
    }

    pack_store(Am + (size_t)i * KP, hA);
    pack_store(Bm + (size_t)i * KP, hB);
}

// global -> LDS direct (1KB per call: 64 lanes x 16B), compiler-visible.
__device__ inline void glds(const unsigned short* p, char* lptr) {
    __builtin_amdgcn_global_load_lds(
        (const __attribute__((address_space(1))) void*)p,
        (__attribute__((address_space(3))) void*)lptr, 16, 0, 0);
}

// 4 single-MFMA chains (64 rows x 16 cols); epilogue (16 exp2 + adds)
// SKIPPED when every g < -40 (wave-uniform test): exp2(g) < 2^-40 each,
// total skipped contribution to the output < 2e-12.
#define BODY4(BHC)                                                           \
    do {                                                                     \
        const f32x4 Z = {0.f, 0.f, 0.f, 0.f};                                \
        f32x4 g0 = MFMA16(ah0, BHC, Z); f32x4 g1 = MFMA16(ah1, BHC, Z);      \
        f32x4 g2 = MFMA16(ah2, BHC, Z); f32x4 g3 = MFMA16(ah3, BHC, Z);      \
        float m0 = fmaxf(fmaxf(fmaxf(g0[0], g0[1]), g0[2]), g0[3]);          \
        float m1 = fmaxf(fmaxf(fmaxf(g1[0], g1[1]), g1[2]), g1[3]);          \
        float m2 = fmaxf(fmaxf(fmaxf(g2[0], g2[1]), g2[2]), g2[3]);          \
        float m3 = fmaxf(fmaxf(fmaxf(g3[0], g3[1]), g3[2]), g3[3]);          \
        float mm = fmaxf(fmaxf(fmaxf(m0, m1), m2), m3);                      \
        if (__any(mm > -40.0f)) {                                            \
            s0 += __builtin_amdgcn_exp2f(g0[0]); s1 += __builtin_amdgcn_exp2f(g0[1]); \
            s2 += __builtin_amdgcn_exp2f(g0[2]); s3 += __builtin_amdgcn_exp2f(g0[3]); \
            s0 += __builtin_amdgcn_exp2f(g1[0]); s1 += __builtin_amdgcn_exp2f(g1[1]); \
            s2 += __builtin_amdgcn_exp2f(g1[2]); s3 += __builtin_amdgcn_exp2f(g1[3]); \
            s0 += __builtin_amdgcn_exp2f(g2[0]); s1 += __builtin_amdgcn_exp2f(g2[1]); \
            s2 += __builtin_amdgcn_exp2f(g2[2]); s3 += __builtin_amdgcn_exp2f(g2[3]); \
            s0 += __builtin_amdgcn_exp2f(g3[0]); s1 += __builtin_amdgcn_exp2f(g3[1]); \
            s2 += __builtin_amdgcn_exp2f(g3[2]); s3 += __builtin_amdgcn_exp2f(g3[3]); \
        }                                                                    \
    } while (0)

// 256x256 tile per 4-wave block. B panel in LDS in TWO double-buffered 8KB
// halves; wave wv owns rows [si*256 + wv*64, +64).
// Barriers do all draining (vmcnt(0)+lgkmcnt(0)): no manual waitcnt.
__global__ __launch_bounds__(256, 4) void gp_pairs24(const unsigned short* __restrict__ Am,
                                                     const unsigned short* __restrict__ Bm,
                                                     float* __restrict__ part) {
    __shared__ __align__(16) char ldsB[2][8192];
    __shared__ float red[4];

    const int phys = blockIdx.x;
    const int blk = (phys & 7) * 528 + (phys >> 3);   // bijective, 4224 = 8*528

    const int t = threadIdx.x;
    const int wv = t >> 6, l = t & 63;
    const int l15 = l & 15, lhi = l >> 4;

    int type, b, si, sj;
    float wt;
    if (blk < XYB) {
        type = 0; b = blk >> 8;
        int rr = blk & 255; si = rr >> 4; sj = rr & 15;
        wt = -2.0f;
    } else {
        int id2 = blk - XYB;
        type = 1 + id2 / 1088;
        int r = id2 % 1088; b = r / 136; int t2 = r % 136;
        sj = (int)((sqrtf(8.0f * (float)t2 + 1.0f) - 1.0f) * 0.5f);
        while ((sj + 1) * (sj + 2) / 2 <= t2) ++sj;
        while (sj * (sj + 1) / 2 > t2) --sj;
        si = t2 - sj * (sj + 1) / 2;                  // si <= sj
        wt = (si == sj) ? 1.0f : 2.0f;
    }
    int imA, imB;
    if (type == 0)      { imA = b;     imB = 8 + b; }
    else if (type == 1) { imA = b;     imB = b;     }
    else                { imA = 8 + b; imB = 8 + b; }

    // A fragments: 64 rows for this wave (4 frags, 16 VGPR), plain loads +
    // keep-alive tie (cannot be sunk/remat'd; barrier 1 drains the loads).
    const size_t eA = ((size_t)(imA * NPAD + si * 256 + wv * 64 + l15)) * KP + lhi * 8;
    const unsigned short* pA = Am + eA;
    bf16x8 ah0 = *(const bf16x8*)(pA);
    bf16x8 ah1 = *(const bf16x8*)(pA + 512);
    bf16x8 ah2 = *(const bf16x8*)(pA + 1024);
    bf16x8 ah3 = *(const bf16x8*)(pA + 1536);
    asm volatile("" : "+v"(ah0), "+v"(ah1), "+v"(ah2), "+v"(ah3));

    const unsigned short* bBase = Bm + ((size_t)(imB * NPAD + sj * 256 + l15)) * KP + lhi * 8;
    // NOTE: col c's fragment lives at bBase + c*KP (c = q*16 + l15 handled
    // via the per-lane l15 in bBase; chunk q adds q*16*KP = q*512 elements).

    // Stage half 0 (cols 0-127): 8 chunks of 1KB; wave wv stages q = wv*2+j.
#pragma unroll
    for (int j = 0; j < 2; ++j) {
        const int q = wv * 2 + j;
        glds(bBase + (size_t)q * 512, &ldsB[0][q * 1024]);
    }
    __syncthreads();   // drains A loads + half0 DMA; half0 readable

    // Issue half 1 (cols 128-255) staging -- in flight under half0 compute.
#pragma unroll
    for (int j = 0; j < 2; ++j) {
        const int q = wv * 2 + j;
        glds(bBase + (size_t)(8 + q) * 512, &ldsB[1][q * 1024]);
    }

    float s0 = 0.f, s1 = 0.f, s2 = 0.f, s3 = 0.f;

    // Compute half 0: 8 cg steps from ldsB[0].
#pragma unroll
    for (int cg = 0; cg < 8; ++cg) {
        const bf16x8 bhc = *(const bf16x8*)(&ldsB[0][cg * 1024] + l * 16);
        BODY4(bhc);
    }

    __syncthreads();   // drains half1 DMA (vmcnt 0); half1 readable

    // Compute half 1: 8 cg steps from ldsB[1].
#pragma unroll
    for (int cg = 0; cg < 8; ++cg) {
        const bf16x8 bhc = *(const bf16x8*)(&ldsB[1][cg * 1024] + l * 16);
        BODY4(bhc);
    }

    float sacc = (s0 + s1) + (s2 + s3);

    // wave reduce; cross-wave combine; one plain store per block (no atomics)
#pragma unroll
    for (int o = 32; o > 0; o >>= 1) sacc += __shfl_down(sacc, o, 64);
    if (l == 0) red[wv] = sacc;
    __syncthreads();
    if (t == 0) part[blk] = wt * ((red[0] + red[1]) + (red[2] + red[3]));
}

// ONE block x 1024 threads (16 waves): coalesced sum of the 4224 weighted
// block partials; answer = sum / (8 N^2).
__global__ __launch_bounds__(1024) void gp_finish(const float* __restrict__ part,
                                                  float* __restrict__ out) {
    __shared__ float red[16];
    const int t = threadIdx.x;
    const int wv = t >> 6, l = t & 63;

    float s = 0.0f;
    for (int i = t; i < NBLK; i += 1024) s += part[i];
#pragma unroll
    for (int o = 32; o > 0; o >>= 1) s += __shfl_down(s, o, 64);
    if (l == 0) red[wv] = s;
    __syncthreads();
    if (t == 0) {
        double d = 0.0;
#pragma unroll
        for (int i = 0; i < 16; ++i) d += (double)red[i];
        out[0] = (float)(d / (8.0 * (double)NP * (double)NP));
    }
}

extern "C" void kernel_launch(void* const* d_in, const int* in_sizes, int n_in,
                              void* d_out, int out_size, void* d_ws, size_t ws_size,
                              hipStream_t stream) {
    const float* x = (const float*)d_in[0];
    const float* y = (const float*)d_in[1];
    const size_t MSZ = (size_t)16 * NPAD * KP;
    unsigned short* Am = (unsigned short*)d_ws;
    unsigned short* Bm = Am + MSZ;
    float* part = (float*)(Bm + MSZ);

    gp_prep<<<(16 * NPAD) / 256, 256, 0, stream>>>(x, y, Am, Bm);
    gp_pairs24<<<NBLK, 256, 0, stream>>>(Am, Bm, part);
    gp_finish<<<1, 1024, 0, stream>>>(part, (float*)d_out);
}

// Round 25
// 37.294 us; speedup vs baseline: 1.0901x; 1.0257x over previous
//
#include <hip/hip_runtime.h>
#include <hip/hip_bf16.h>

// GlobalPoolDistance: RBF-kernel MMD over 3x3 patch unfolds (8,3,64,64) f32.
// N = 62*62 = 3844 patches, d = 27 (padded K=32). SIG2 = 0.2916.
// R25 = exact revert to R22 (session best, 37.07us). R24's half-tile double
// buffer measured neutral-negative (38.3); R23's 512^2 tiles regressed
// (40.7); R21's launch-merge was null -> the remaining wall is a fixed
// launch/replay floor, and R22 is the verified optimum.
// Structure: 256x256 tile per 4-wave block; B panel (16KB, single matrix)
// staged ONCE into LDS via global_load_lds and shared by 4 waves; A = 4
// frags/wave in registers (plain loads + empty-asm keep-alive tie, R14);
// ONE __syncthreads whose vmcnt(0) drain covers A loads + staging DMA (no
// manual vmcnt anywhere -- R11/R13 lesson). 0.5 B/pair -> 122 MB L2 traffic.
// Math: single-MFMA gram (diag exact by construction: p = -s'/2 over the
// ROUNDED bf16 values, baked hi/lo across pad-col pairs 27/28 x B=1 and
// 29/30 x A=1); negligible-fragment skip (epilogue only when __any(g > -40);
// skipped values < 2^-40 each, total < 2e-12 vs 1e-5 threshold); combine
// weights folded into the store (xy=-2, sym diag=+1, off-diag=+2) ->
// answer = sum(part)/(8N^2). 4224 = 8*528 bijective XCD swizzle.
// Ladder: 328 (R1 VALU) -> 182 (MFMA split-bf16) -> 83.5 (LDS tiles) ->
// 61 (p-bake) -> 49.5 (no atomics) -> 47 (single-MFMA) -> 39.6 (skip +
// 8-deep prefetch) -> 37.1 (B-share, 0.5 B/pair).
//
// ws: Am|Bm [16][4096][32] bf16 (2 x 4,194,304 B) + part[4224] f32.

#define NP    3844
#define NPAD  4096
#define KP    32

#define XYB   2048     // 8 * 16 * 16 xy tile-blocks
#define NBLK  4224     // + 2 * 8 * 136 tri tile-blocks = 8 * 528

static constexpr float L_F   = 4.9475824173972215f;   // log2(e)/0.2916
static constexpr float C2L_F = 9.895164834794443f;    // 2*L

using bf16x8 = __attribute__((ext_vector_type(8))) short;
using f32x4  = __attribute__((ext_vector_type(4))) float;

#define MFMA16(a, b, c) __builtin_amdgcn_mfma_f32_16x16x32_bf16((a), (b), (c), 0, 0, 0)

__device__ inline unsigned short f2bf(float f) {
    union { float f; unsigned u; } v; v.f = f;
    unsigned r = v.u + 0x7FFFu + ((v.u >> 16) & 1u);   // RNE (no NaN inputs)
    return (unsigned short)(r >> 16);
}
__device__ inline float bf2f(unsigned short h) {
    union { unsigned u; float f; } v; v.u = ((unsigned)h) << 16;
    return v.f;
}
__device__ inline void pack_store(unsigned short* dst, const unsigned short* v) {
    uint4* d = (uint4*)dst;
#pragma unroll
    for (int q = 0; q < 4; ++q) {
        unsigned w0 = (unsigned)v[8 * q + 0] | ((unsigned)v[8 * q + 1] << 16);
        unsigned w1 = (unsigned)v[8 * q + 2] | ((unsigned)v[8 * q + 3] << 16);
        unsigned w2 = (unsigned)v[8 * q + 4] | ((unsigned)v[8 * q + 5] << 16);
        unsigned w3 = (unsigned)v[8 * q + 6] | ((unsigned)v[8 * q + 7] << 16);
        d[q] = make_uint4(w0, w1, w2, w3);
    }
}

// One thread per (im, patch). A data = bf16(2L*v); B data = bf16(v);
// s' = sum over ROUNDED values; p = -s'/2 split hi/lo across column pairs.
__global__ __launch_bounds__(256) void gp_prep(const float* __restrict__ x,
                                               const float* __restrict__ y,
                                               unsigned short* __restrict__ Am,
                                               unsigned short* __restrict__ Bm) {
    int i = blockIdx.x * 256 + threadIdx.x;          // 16*NPAD = 65536
    if (i >= 16 * NPAD) return;
    int n = i % NPAD, im = i / NPAD;
    int b = im & 7;
    const float* src = (im >> 3) ? y : x;

    const unsigned short ONE = f2bf(1.0f);           // exact
    unsigned short hA[32], hB[32];
#pragma unroll
    for (int k = 0; k < 32; ++k) { hA[k] = 0; hB[k] = 0; }

    if (n < NP) {
        int r = n / 62, c = n % 62;
        float s = 0.0f;
#pragma unroll
        for (int ch = 0; ch < 3; ++ch)
#pragma unroll
            for (int pr = 0; pr < 3; ++pr)
#pragma unroll
                for (int pc = 0; pc < 3; ++pc) {
                    int k = ch * 9 + pr * 3 + pc;
                    float v = src[(((b * 3 + ch) * 64) + r + pr) * 64 + (c + pc)];
                    unsigned short ah = f2bf(C2L_F * v);
                    unsigned short bh = f2bf(v);
                    hA[k] = ah; hB[k] = bh;
                    s = fmaf(bf2f(ah), bf2f(bh), s);   // s' over ROUNDED values
                }
        float p = -0.5f * s;
        // A-side p: cols 27(hi)/28(lo), matched by B27=B28=1
        hA[27] = f2bf(p); hA[28] = f2bf(p - bf2f(hA[27]));
        hA[29] = ONE; hA[30] = ONE;
        // B-side p: cols 29(hi)/30(lo), matched by A29=A30=1
        hB[27] = ONE; hB[28] = ONE;
        hB[29] = f2bf(p); hB[30] = f2bf(p - bf2f(hB[29]));
    } else {
        // phantom: row/col contributes exp2(-1e30) = 0 against real AND phantom
        hA[27] = f2bf(-1e30f); hA[29] = ONE; hA[30] = ONE;
        hB[27] = ONE; hB[28] = ONE; hB[29] = f2bf(-1e30f);
    }

    pack_store(Am + (size_t)i * KP, hA);
    pack_store(Bm + (size_t)i * KP, hB);
}

// global -> LDS direct (1KB per call: 64 lanes x 16B), compiler-visible.
__device__ inline void glds(const unsigned short* p, char* lptr) {
    __builtin_amdgcn_global_load_lds(
        (const __attribute__((address_space(1))) void*)p,
        (__attribute__((address_space(3))) void*)lptr, 16, 0, 0);
}

// 4 single-MFMA chains (64 rows x 16 cols); epilogue (16 exp2 + adds)
// SKIPPED when every g < -40 (wave-uniform test): exp2(g) < 2^-40 each,
// total skipped contribution to the output < 2e-12.
#define BODY4(BHC)                                                           \
    do {                                                                     \
        const f32x4 Z = {0.f, 0.f, 0.f, 0.f};                                \
        f32x4 g0 = MFMA16(ah0, BHC, Z); f32x4 g1 = MFMA16(ah1, BHC, Z);      \
        f32x4 g2 = MFMA16(ah2, BHC, Z); f32x4 g3 = MFMA16(ah3, BHC, Z);      \
        float m0 = fmaxf(fmaxf(fmaxf(g0[0], g0[1]), g0[2]), g0[3]);          \
        float m1 = fmaxf(fmaxf(fmaxf(g1[0], g1[1]), g1[2]), g1[3]);          \
        float m2 = fmaxf(fmaxf(fmaxf(g2[0], g2[1]), g2[2]), g2[3]);          \
        float m3 = fmaxf(fmaxf(fmaxf(g3[0], g3[1]), g3[2]), g3[3]);          \
        float mm = fmaxf(fmaxf(fmaxf(m0, m1), m2), m3);                      \
        if (__any(mm > -40.0f)) {                                            \
            s0 += __builtin_amdgcn_exp2f(g0[0]); s1 += __builtin_amdgcn_exp2f(g0[1]); \
            s2 += __builtin_amdgcn_exp2f(g0[2]); s3 += __builtin_amdgcn_exp2f(g0[3]); \
            s0 += __builtin_amdgcn_exp2f(g1[0]); s1 += __builtin_amdgcn_exp2f(g1[1]); \
            s2 += __builtin_amdgcn_exp2f(g1[2]); s3 += __builtin_amdgcn_exp2f(g1[3]); \
            s0 += __builtin_amdgcn_exp2f(g2[0]); s1 += __builtin_amdgcn_exp2f(g2[1]); \
            s2 += __builtin_amdgcn_exp2f(g2[2]); s3 += __builtin_amdgcn_exp2f(g2[3]); \
            s0 += __builtin_amdgcn_exp2f(g3[0]); s1 += __builtin_amdgcn_exp2f(g3[1]); \
            s2 += __builtin_amdgcn_exp2f(g3[2]); s3 += __builtin_amdgcn_exp2f(g3[3]); \
        }                                                                    \
    } while (0)

// 256x256 tile per 4-wave block. B panel (single matrix, 16KB) in LDS
// shared by all 4 waves; wave wv owns rows [si*256 + wv*64, +64).
// No manual waitcnt: __syncthreads' vmcnt(0) drain covers A plain loads
// (kept live by the empty-asm tie) and the B staging DMA.
__global__ __launch_bounds__(256, 4) void gp_pairs25(const unsigned short* __restrict__ Am,
                                                     const unsigned short* __restrict__ Bm,
                                                     float* __restrict__ part) {
    __shared__ __align__(16) char ldsB[16384];
    __shared__ float red[4];

    const int phys = blockIdx.x;
    const int blk = (phys & 7) * 528 + (phys >> 3);   // bijective, 4224 = 8*528

    const int t = threadIdx.x;
    const int wv = t >> 6, l = t & 63;
    const int l15 = l & 15, lhi = l >> 4;

    int type, b, si, sj;
    float wt;
    if (blk < XYB) {
        type = 0; b = blk >> 8;
        int rr = blk & 255; si = rr >> 4; sj = rr & 15;
        wt = -2.0f;
    } else {
        int id2 = blk - XYB;
        type = 1 + id2 / 1088;
        int r = id2 % 1088; b = r / 136; int t2 = r % 136;
        sj = (int)((sqrtf(8.0f * (float)t2 + 1.0f) - 1.0f) * 0.5f);
        while ((sj + 1) * (sj + 2) / 2 <= t2) ++sj;
        while (sj * (sj + 1) / 2 > t2) --sj;
        si = t2 - sj * (sj + 1) / 2;                  // si <= sj
        wt = (si == sj) ? 1.0f : 2.0f;
    }
    int imA, imB;
    if (type == 0)      { imA = b;     imB = 8 + b; }
    else if (type == 1) { imA = b;     imB = b;     }
    else                { imA = 8 + b; imB = 8 + b; }

    // A fragments: 64 rows for this wave (4 frags, 16 VGPR), plain loads +
    // keep-alive tie (cannot be sunk/remat'd; syncthreads drains the loads).
    const size_t eA = ((size_t)(imA * NPAD + si * 256 + wv * 64 + l15)) * KP + lhi * 8;
    const unsigned short* pA = Am + eA;
    bf16x8 ah0 = *(const bf16x8*)(pA);
    bf16x8 ah1 = *(const bf16x8*)(pA + 512);
    bf16x8 ah2 = *(const bf16x8*)(pA + 1024);
    bf16x8 ah3 = *(const bf16x8*)(pA + 1536);
    asm volatile("" : "+v"(ah0), "+v"(ah1), "+v"(ah2), "+v"(ah3));

    // Stage the 256-col B panel (16KB) cooperatively: 16 chunks of 1KB;
    // wave wv stages chunks wv*4..wv*4+3 (wave-uniform LDS dst, per-lane src).
#pragma unroll
    for (int j = 0; j < 4; ++j) {
        const int q = wv * 4 + j;
        const unsigned short* src = Bm
            + ((size_t)(imB * NPAD + sj * 256 + q * 16 + l15)) * KP + lhi * 8;
        glds(src, ldsB + q * 1024);
    }
    __syncthreads();   // vmcnt(0)+lgkmcnt(0) drain (A loads + staging) + barrier

    float s0 = 0.f, s1 = 0.f, s2 = 0.f, s3 = 0.f;

    // 16 barrier-free cg steps: B frag from LDS (conflict-free lane*16B),
    // 4 MFMA + skip-guarded 16 exp2 each.
#pragma unroll
    for (int cg = 0; cg < 16; ++cg) {
        const bf16x8 bhc = *(const bf16x8*)(ldsB + cg * 1024 + l * 16);
        BODY4(bhc);
    }

    float sacc = (s0 + s1) + (s2 + s3);

    // wave reduce; cross-wave combine; one plain store per block (no atomics)
#pragma unroll
    for (int o = 32; o > 0; o >>= 1) sacc += __shfl_down(sacc, o, 64);
    if (l == 0) red[wv] = sacc;
    __syncthreads();
    if (t == 0) part[blk] = wt * ((red[0] + red[1]) + (red[2] + red[3]));
}

// ONE block x 1024 threads (16 waves): coalesced sum of the 4224 weighted
// block partials; answer = sum / (8 N^2).
__global__ __launch_bounds__(1024) void gp_finish(const float* __restrict__ part,
                                                  float* __restrict__ out) {
    __shared__ float red[16];
    const int t = threadIdx.x;
    const int wv = t >> 6, l = t & 63;

    float s = 0.0f;
    for (int i = t; i < NBLK; i += 1024) s += part[i];
#pragma unroll
    for (int o = 32; o > 0; o >>= 1) s += __shfl_down(s, o, 64);
    if (l == 0) red[wv] = s;
    __syncthreads();
    if (t == 0) {
        double d = 0.0;
#pragma unroll
        for (int i = 0; i < 16; ++i) d += (double)red[i];
        out[0] = (float)(d / (8.0 * (double)NP * (double)NP));
    }
}

extern "C" void kernel_launch(void* const* d_in, const int* in_sizes, int n_in,
                              void* d_out, int out_size, void* d_ws, size_t ws_size,
                              hipStream_t stream) {
    const float* x = (const float*)d_in[0];
    const float* y = (const float*)d_in[1];
    const size_t MSZ = (size_t)16 * NPAD * KP;
    unsigned short* Am = (unsigned short*)d_ws;
    unsigned short* Bm = Am + MSZ;
    float* part = (float*)(Bm + MSZ);

    gp_prep<<<(16 * NPAD) / 256, 256, 0, stream>>>(x, y, Am, Bm);
    gp_pairs25<<<NBLK, 256, 0, stream>>>(Am, Bm, part);
    gp_finish<<<1, 1024, 0, stream>>>(part, (float*)d_out);
}